// Round 1
// baseline (387.336 us; speedup 1.0000x reference)
//
#include <hip/hip_runtime.h>
#include <stdint.h>

typedef unsigned int u32;
typedef unsigned long long u64;

#define MOD_P 2013265921u

// table offsets (u32 indices into ws)
#define OFF_WTAB    0          // w^i, i<16384
#define OFF_WTABS   16384
#define OFF_W128    32768      // (w^128)^i, i<16384
#define OFF_W128S   49152
#define OFF_RTAB    65536      // (w^16384)^i, i<64   (stage twiddles, order-128 root)
#define OFF_RTABS   65600
#define OFF_CL      65664      // c^i, i<16384        (coset low table)
#define OFF_CLS     82048
#define OFF_CH      98432      // c^(16384*i), i<128  (coset high table)
#define OFF_CHS     98560
#define OFF_NINV    98688      // [ninv, ninv_shoup]

__device__ __forceinline__ u32 mul64mod(u32 a, u32 b){ return (u32)((u64)a * b % MOD_P); }

__device__ u32 powmod(u32 b, u32 e){
  u32 r = 1;
  while (e){ if (e & 1) r = mul64mod(r, b); b = mul64mod(b, b); e >>= 1; }
  return r;
}

__device__ __forceinline__ u32 shoup_of(u32 v){ return (u32)(((u64)v << 32) / MOD_P); }

// Shoup modular multiply: w < P precomputed, ws = floor(w*2^32/P). Result in [0,P).
__device__ __forceinline__ u32 mul_shoup(u32 a, u32 w, u32 ws){
  u32 q = __umulhi(a, ws);
  u32 r = a * w - q * MOD_P;           // exact mod 2^32, true value < 2P
  return (r >= MOD_P) ? r - MOD_P : r;
}

__device__ __forceinline__ int br7(int x){ return (int)(__brev((u32)x) >> 25); }

// XOR-swizzled LDS index for a 128x128 u32 tile: conflict-free in every phase.
__device__ __forceinline__ int lidx(int r, int c){ return (r << 7) | (c ^ (r & 31)); }

// ---------------- table generation (per launch; reads direction flag) -------
extern "C" __global__ void k_gen(u32* __restrict__ ws, const int* __restrict__ f_intt){
  const int idx = blockIdx.x * 256 + threadIdx.x;
  const int intt = f_intt[0];
  u32 w = powmod(31u, (MOD_P - 1) >> 21);     // primitive 2^21-th root
  if (intt) w = powmod(w, MOD_P - 2);         // inverse root for INTT
  if (idx < 16384){
    u32 v = powmod(w, (u32)idx);
    ws[OFF_WTAB + idx] = v;  ws[OFF_WTABS + idx] = shoup_of(v);
    u32 w128 = powmod(w, 128u);
    u32 v2 = powmod(w128, (u32)idx);
    ws[OFF_W128 + idx] = v2; ws[OFF_W128S + idx] = shoup_of(v2);
    u32 c = intt ? powmod(7u, MOD_P - 2) : 7u;    // COSET or its inverse
    u32 cv = powmod(c, (u32)idx);
    ws[OFF_CL + idx] = cv;   ws[OFF_CLS + idx] = shoup_of(cv);
    if (idx < 128){
      u32 chv = powmod(c, (u32)idx << 14);
      ws[OFF_CH + idx] = chv; ws[OFF_CHS + idx] = shoup_of(chv);
    }
    if (idx < 64){
      u32 R = powmod(w, 1u << 14);               // order-128 root
      u32 rv = powmod(R, (u32)idx);
      ws[OFF_RTAB + idx] = rv; ws[OFF_RTABS + idx] = shoup_of(rv);
    }
    if (idx == 0){
      u32 ninv = powmod(1u << 21, MOD_P - 2);
      ws[OFF_NINV] = ninv; ws[OFF_NINV + 1] = shoup_of(ninv);
    }
  }
}

// -------- 128-pt DIF NTT along the ROW dimension of the LDS tile -----------
// natural-order in, out[r] holds frequency br7(r)
__device__ void ntt128_rows(u32* lds, const u32* __restrict__ tw){
  const int t = threadIdx.x;
  const int col = t & 127;
  const int bhi = t >> 7;                 // 0..1
  for (int s = 6; s >= 0; --s){
    const int h = 1 << s;
    __syncthreads();
    #pragma unroll 4
    for (int i = 0; i < 32; ++i){
      int beta = bhi + (i << 1);          // butterfly index 0..63
      int tt = beta & (h - 1);
      int p1 = ((beta ^ tt) << 1) | tt;   // block*2h + tt
      int p2 = p1 + h;
      u32 e = lds[lidx(p1, col)];
      u32 o = lds[lidx(p2, col)];
      u32 sum = e + o;           if (sum >= MOD_P) sum -= MOD_P;
      u32 dif = e + MOD_P - o;   if (dif >= MOD_P) dif -= MOD_P;
      int te = tt << (6 - s);
      dif = mul_shoup(dif, tw[OFF_RTAB + te], tw[OFF_RTABS + te]);
      lds[lidx(p1, col)] = sum;
      lds[lidx(p2, col)] = dif;
    }
  }
  __syncthreads();
}

// -------- 128-pt DIF NTT along the COLUMN dimension (rows are spectators) ---
__device__ void ntt128_cols(u32* lds, const u32* __restrict__ tw){
  const int t = threadIdx.x;
  const int beta = t & 63;
  const int rhi = t >> 6;                 // 0..3
  for (int s = 6; s >= 0; --s){
    const int h = 1 << s;
    const int tt = beta & (h - 1);
    const int p1 = ((beta ^ tt) << 1) | tt;
    const int p2 = p1 + h;
    const int te = tt << (6 - s);
    const u32 twv = tw[OFF_RTAB + te];
    const u32 tws = tw[OFF_RTABS + te];
    __syncthreads();
    #pragma unroll 4
    for (int i = 0; i < 32; ++i){
      int row = rhi + (i << 2);
      u32 e = lds[lidx(row, p1)];
      u32 o = lds[lidx(row, p2)];
      u32 sum = e + o;           if (sum >= MOD_P) sum -= MOD_P;
      u32 dif = e + MOD_P - o;   if (dif >= MOD_P) dif -= MOD_P;
      dif = mul_shoup(dif, twv, tws);
      lds[lidx(row, p1)] = sum;
      lds[lidx(row, p2)] = dif;
    }
  }
  __syncthreads();
}

// ---------------- pass A: NTT over ja (stride 16384), d_in -> d_out ---------
extern "C" __global__ void __launch_bounds__(256) k_passA(
    const u32* __restrict__ x, u32* __restrict__ y, const u32* __restrict__ tw,
    const int* __restrict__ f_intt, const int* __restrict__ f_coset)
{
  __shared__ u32 lds[16384];
  const int wg = blockIdx.x;
  const int batch = wg >> 7;
  const int jb = wg & 127;
  const u32* xb = x + ((size_t)batch << 21);
  u32* yb = y + ((size_t)batch << 21);
  const int t = threadIdx.x;
  const int jc = t & 127;
  const int rhi = t >> 7;
  const bool pre = (f_intt[0] == 0) && (f_coset[0] != 0);
  #pragma unroll 4
  for (int i = 0; i < 64; ++i){
    int ja = rhi + (i << 1);
    u32 v = xb[((size_t)ja << 14) + (jb << 7) + jc];
    if (v >= MOD_P) v -= MOD_P;
    if (pre){
      int jlo = (jb << 7) + jc;
      v = mul_shoup(v, tw[OFF_CL + jlo], tw[OFF_CLS + jlo]);
      v = mul_shoup(v, tw[OFF_CH + ja], tw[OFF_CHS + ja]);
    }
    lds[lidx(ja, jc)] = v;
  }
  ntt128_rows(lds, tw);
  #pragma unroll 4
  for (int i = 0; i < 64; ++i){
    int r = rhi + (i << 1);
    int ka = br7(r);
    u32 v = lds[lidx(r, jc)];
    int e1 = ka * jc;
    v = mul_shoup(v, tw[OFF_WTAB + e1], tw[OFF_WTABS + e1]);
    int e2 = ka * jb;
    v = mul_shoup(v, tw[OFF_W128 + e2], tw[OFF_W128S + e2]);
    yb[((size_t)ka << 14) + (jb << 7) + jc] = v;
  }
}

// ---------------- pass B: NTT over jb (contiguous slab, in-place) -----------
extern "C" __global__ void __launch_bounds__(256) k_passB(
    u32* __restrict__ y, const u32* __restrict__ tw)
{
  __shared__ u32 lds[16384];
  const int wg = blockIdx.x;
  const int batch = wg >> 7;
  const int ka = wg & 127;
  u32* yb = y + ((size_t)batch << 21) + ((size_t)ka << 14);
  const int t = threadIdx.x;
  const int jc = t & 127;
  const int rhi = t >> 7;
  #pragma unroll 4
  for (int i = 0; i < 64; ++i){
    int jb = rhi + (i << 1);
    lds[lidx(jb, jc)] = yb[(jb << 7) + jc];
  }
  ntt128_rows(lds, tw);
  #pragma unroll 4
  for (int i = 0; i < 64; ++i){
    int r = rhi + (i << 1);
    int kb = br7(r);
    u32 v = lds[lidx(r, jc)];
    int e = jc * kb;
    v = mul_shoup(v, tw[OFF_W128 + e], tw[OFF_W128S + e]);
    yb[(kb << 7) + jc] = v;
  }
}

// ------- pass C: NTT over jc + in-place plane transpose to final order ------
extern "C" __global__ void __launch_bounds__(256) k_passC(
    u32* __restrict__ y, const u32* __restrict__ tw,
    const int* __restrict__ f_intt, const int* __restrict__ f_coset)
{
  __shared__ u32 lds[16384];
  const int wg = blockIdx.x;
  const int batch = wg >> 7;
  const int kb = wg & 127;
  u32* yb = y + ((size_t)batch << 21);
  const int t = threadIdx.x;
  const int c = t & 127;
  const int rhi = t >> 7;
  #pragma unroll 4
  for (int i = 0; i < 64; ++i){
    int ka = rhi + (i << 1);
    lds[lidx(ka, c)] = yb[((size_t)ka << 14) + (kb << 7) + c];
  }
  ntt128_cols(lds, tw);
  const int intt = f_intt[0];
  const int coset = f_coset[0];
  const int ka2 = t & 127;
  #pragma unroll 4
  for (int i = 0; i < 64; ++i){
    int pos = rhi + (i << 1);
    int kc = br7(pos);
    u32 v = lds[lidx(ka2, pos)];
    if (intt){
      v = mul_shoup(v, tw[OFF_NINV], tw[OFF_NINV + 1]);
      if (coset){
        int klo = (kb << 7) + ka2;
        v = mul_shoup(v, tw[OFF_CL + klo], tw[OFF_CLS + klo]);
        v = mul_shoup(v, tw[OFF_CH + kc], tw[OFF_CHS + kc]);
      }
    }
    yb[((size_t)kc << 14) + (kb << 7) + ka2] = v;   // flat index = ka+128*kb+16384*kc
  }
}

extern "C" void kernel_launch(void* const* d_in, const int* in_sizes, int n_in,
                              void* d_out, int out_size, void* d_ws, size_t ws_size,
                              hipStream_t stream)
{
  const u32* x = (const u32*)d_in[0];
  const int* f_intt  = (const int*)d_in[1];
  const int* f_coset = (const int*)d_in[2];
  u32* y  = (u32*)d_out;
  u32* tw = (u32*)d_ws;
  const int batch = in_sizes[0] >> 21;     // 8
  const int nwg = batch << 7;              // 1024 workgroups per pass

  k_gen  <<<64,  256, 0, stream>>>(tw, f_intt);
  k_passA<<<nwg, 256, 0, stream>>>(x, y, tw, f_intt, f_coset);
  k_passB<<<nwg, 256, 0, stream>>>(y, tw);
  k_passC<<<nwg, 256, 0, stream>>>(y, tw, f_intt, f_coset);
}

// Round 2
// 291.795 us; speedup vs baseline: 1.3274x; 1.3274x over previous
//
#include <hip/hip_runtime.h>
#include <stdint.h>

typedef unsigned int u32;
typedef unsigned long long u64;

#define MOD_P 2013265921u

// uint2 table offsets (index in uint2 units): (value, shoup) pairs
#define T_WP     0        // (w^i),        i<16384
#define T_W128P  16384    // ((w^128)^i),  i<16384
#define T_RP     32768    // ((w^16384)^i), i<64   (order-128 stage roots)
#define T_CLP    32832    // (c^i),        i<16384 (coset low)
#define T_CHP    49216    // (c^(16384 i)), i<128  (coset high)
#define T_NINV   49344    // (n^-1)

__device__ __forceinline__ u32 mul64mod(u32 a, u32 b){ return (u32)((u64)a * b % MOD_P); }

__device__ u32 powmod(u32 b, u32 e){
  u32 r = 1;
  while (e){ if (e & 1) r = mul64mod(r, b); b = mul64mod(b, b); e >>= 1; }
  return r;
}

__device__ __forceinline__ u32 shoup_of(u32 v){ return (u32)(((u64)v << 32) / MOD_P); }

// Shoup modular multiply with precomputed (w, floor(w*2^32/P)). Result in [0,P).
__device__ __forceinline__ u32 mul_shoup(u32 a, uint2 t){
  u32 q = __umulhi(a, t.y);
  u32 r = a * t.x - q * MOD_P;          // exact mod 2^32, true value < 2P
  return (r >= MOD_P) ? r - MOD_P : r;
}

__device__ __forceinline__ int br7(int x){ return (int)(__brev((u32)x) >> 25); }

// XOR-swizzled LDS index for a 128x128 u32 tile.
__device__ __forceinline__ int lidx(int r, int c){ return (r << 7) | (c ^ (r & 31)); }

// ---------------- table generation (per launch; reads direction flag) -------
extern "C" __global__ void k_gen(uint2* __restrict__ tw, const int* __restrict__ f_intt){
  const int idx = blockIdx.x * 256 + threadIdx.x;
  const int intt = f_intt[0];
  u32 w = powmod(31u, (MOD_P - 1) >> 21);     // primitive 2^21-th root
  if (intt) w = powmod(w, MOD_P - 2);
  if (idx < 16384){
    u32 v = powmod(w, (u32)idx);
    tw[T_WP + idx] = make_uint2(v, shoup_of(v));
    u32 v2 = powmod(powmod(w, 128u), (u32)idx);
    tw[T_W128P + idx] = make_uint2(v2, shoup_of(v2));
    u32 c = intt ? powmod(7u, MOD_P - 2) : 7u;
    u32 cv = powmod(c, (u32)idx);
    tw[T_CLP + idx] = make_uint2(cv, shoup_of(cv));
    if (idx < 128){
      u32 h = powmod(c, (u32)idx << 14);
      tw[T_CHP + idx] = make_uint2(h, shoup_of(h));
    }
    if (idx < 64){
      u32 rv = powmod(powmod(w, 1u << 14), (u32)idx);
      tw[T_RP + idx] = make_uint2(rv, shoup_of(rv));
    }
    if (idx == 0){
      u32 ninv = powmod(1u << 21, MOD_P - 2);
      tw[T_NINV] = make_uint2(ninv, shoup_of(ninv));
    }
  }
}

// -------- 128-pt DIF NTT along the ROW dimension (512 threads) --------------
// natural-order in, out[r] holds frequency br7(r)
__device__ void ntt128_rows(u32* lds, const uint2* __restrict__ tw){
  const int t = threadIdx.x;
  const int col = t & 127;
  const int bhi = t >> 7;                 // 0..3, wave-uniform
  for (int s = 6; s >= 0; --s){
    const int h = 1 << s;
    __syncthreads();
    #pragma unroll
    for (int i = 0; i < 16; ++i){
      int beta = bhi + (i << 2);          // butterfly index 0..63
      int tt = beta & (h - 1);
      int p1 = ((beta ^ tt) << 1) | tt;
      int p2 = p1 + h;
      u32 e = lds[lidx(p1, col)];
      u32 o = lds[lidx(p2, col)];
      u32 sum = e + o;           if (sum >= MOD_P) sum -= MOD_P;
      u32 dif = e + MOD_P - o;   if (dif >= MOD_P) dif -= MOD_P;
      dif = mul_shoup(dif, tw[T_RP + (tt << (6 - s))]);
      lds[lidx(p1, col)] = sum;
      lds[lidx(p2, col)] = dif;
    }
  }
  __syncthreads();
}

// -------- 128-pt DIF NTT along the COLUMN dimension (512 threads) -----------
__device__ void ntt128_cols(u32* lds, const uint2* __restrict__ tw){
  const int t = threadIdx.x;
  const int beta = t & 63;
  const int rhi = t >> 6;                 // 0..7
  for (int s = 6; s >= 0; --s){
    const int h = 1 << s;
    const int tt = beta & (h - 1);
    const int p1 = ((beta ^ tt) << 1) | tt;
    const int p2 = p1 + h;
    const uint2 tv = tw[T_RP + (tt << (6 - s))];
    __syncthreads();
    #pragma unroll
    for (int i = 0; i < 16; ++i){
      int row = rhi + (i << 3);
      u32 e = lds[lidx(row, p1)];
      u32 o = lds[lidx(row, p2)];
      u32 sum = e + o;           if (sum >= MOD_P) sum -= MOD_P;
      u32 dif = e + MOD_P - o;   if (dif >= MOD_P) dif -= MOD_P;
      dif = mul_shoup(dif, tv);
      lds[lidx(row, p1)] = sum;
      lds[lidx(row, p2)] = dif;
    }
  }
  __syncthreads();
}

// ---------------- pass A: NTT over ja (stride 16384), d_in -> d_out ---------
extern "C" __global__ void __launch_bounds__(512, 4) k_passA(
    const u32* __restrict__ x, u32* __restrict__ y, const uint2* __restrict__ tw,
    const int* __restrict__ f_intt, const int* __restrict__ f_coset)
{
  __shared__ u32 lds[16384];
  const int wg = blockIdx.x;
  const int batch = wg >> 7;
  const int jb = wg & 127;
  const u32* xb = x + ((size_t)batch << 21);
  u32* yb = y + ((size_t)batch << 21);
  const int t = threadIdx.x;
  const int q = t & 31;                  // quad-column 0..31
  const int roff = t >> 5;               // 0..15
  const bool pre = (f_intt[0] == 0) && (f_coset[0] != 0);
  #pragma unroll
  for (int i = 0; i < 8; ++i){
    int ja = roff + (i << 4);
    uint4 v4 = *(const uint4*)(xb + ((size_t)ja << 14) + (jb << 7) + (q << 2));
    u32 vv[4] = {v4.x, v4.y, v4.z, v4.w};
    #pragma unroll
    for (int j = 0; j < 4; ++j){
      u32 v = vv[j];
      if (v >= MOD_P) v -= MOD_P;
      if (pre){
        int jlo = (jb << 7) + (q << 2) + j;
        v = mul_shoup(v, tw[T_CLP + jlo]);
        v = mul_shoup(v, tw[T_CHP + ja]);
      }
      lds[lidx(ja, (q << 2) + j)] = v;
    }
  }
  ntt128_rows(lds, tw);
  #pragma unroll
  for (int i = 0; i < 8; ++i){
    int r = roff + (i << 4);
    int ka = br7(r);
    uint2 t2 = tw[T_W128P + ka * jb];    // wave-uniform
    u32 ov[4];
    #pragma unroll
    for (int j = 0; j < 4; ++j){
      int c = (q << 2) + j;
      u32 v = lds[lidx(r, c)];
      v = mul_shoup(v, tw[T_WP + ka * c]);
      v = mul_shoup(v, t2);
      ov[j] = v;
    }
    *(uint4*)(yb + ((size_t)ka << 14) + (jb << 7) + (q << 2)) = make_uint4(ov[0], ov[1], ov[2], ov[3]);
  }
}

// ---------------- pass B: NTT over jb (contiguous slab, in-place) -----------
extern "C" __global__ void __launch_bounds__(512, 4) k_passB(
    u32* __restrict__ y, const uint2* __restrict__ tw)
{
  __shared__ u32 lds[16384];
  const int wg = blockIdx.x;
  const int batch = wg >> 7;
  const int ka = wg & 127;
  u32* yb = y + ((size_t)batch << 21) + ((size_t)ka << 14);
  const int t = threadIdx.x;
  const int q = t & 31;
  const int roff = t >> 5;
  #pragma unroll
  for (int i = 0; i < 8; ++i){
    int jb = roff + (i << 4);
    uint4 v4 = *(const uint4*)(yb + (jb << 7) + (q << 2));
    lds[lidx(jb, (q << 2) + 0)] = v4.x;
    lds[lidx(jb, (q << 2) + 1)] = v4.y;
    lds[lidx(jb, (q << 2) + 2)] = v4.z;
    lds[lidx(jb, (q << 2) + 3)] = v4.w;
  }
  ntt128_rows(lds, tw);
  #pragma unroll
  for (int i = 0; i < 8; ++i){
    int r = roff + (i << 4);
    int kb = br7(r);
    u32 ov[4];
    #pragma unroll
    for (int j = 0; j < 4; ++j){
      int c = (q << 2) + j;
      u32 v = lds[lidx(r, c)];
      v = mul_shoup(v, tw[T_W128P + c * kb]);
      ov[j] = v;
    }
    *(uint4*)(yb + (kb << 7) + (q << 2)) = make_uint4(ov[0], ov[1], ov[2], ov[3]);
  }
}

// ------- pass C: NTT over jc + in-place plane transpose to final order ------
extern "C" __global__ void __launch_bounds__(512, 4) k_passC(
    u32* __restrict__ y, const uint2* __restrict__ tw,
    const int* __restrict__ f_intt, const int* __restrict__ f_coset)
{
  __shared__ u32 lds[16384];
  const int wg = blockIdx.x;
  const int batch = wg >> 7;
  const int kb = wg & 127;
  u32* yb = y + ((size_t)batch << 21);
  const int t = threadIdx.x;
  const int q = t & 31;
  const int roff = t >> 5;
  #pragma unroll
  for (int i = 0; i < 8; ++i){
    int ka = roff + (i << 4);
    uint4 v4 = *(const uint4*)(yb + ((size_t)ka << 14) + (kb << 7) + (q << 2));
    lds[lidx(ka, (q << 2) + 0)] = v4.x;
    lds[lidx(ka, (q << 2) + 1)] = v4.y;
    lds[lidx(ka, (q << 2) + 2)] = v4.z;
    lds[lidx(ka, (q << 2) + 3)] = v4.w;
  }
  ntt128_cols(lds, tw);
  const int intt = f_intt[0];
  const int coset = f_coset[0];
  const int ka2 = t & 127;
  const int rr = t >> 7;                 // 0..3
  #pragma unroll
  for (int i = 0; i < 32; ++i){
    int pos = rr + (i << 2);
    int kc = br7(pos);
    u32 v = lds[lidx(ka2, pos)];
    if (intt){
      v = mul_shoup(v, tw[T_NINV]);
      if (coset){
        int klo = (kb << 7) + ka2;
        v = mul_shoup(v, tw[T_CLP + klo]);
        v = mul_shoup(v, tw[T_CHP + kc]);
      }
    }
    yb[((size_t)kc << 14) + (kb << 7) + ka2] = v;   // flat = ka + 128*kb + 16384*kc
  }
}

extern "C" void kernel_launch(void* const* d_in, const int* in_sizes, int n_in,
                              void* d_out, int out_size, void* d_ws, size_t ws_size,
                              hipStream_t stream)
{
  const u32* x = (const u32*)d_in[0];
  const int* f_intt  = (const int*)d_in[1];
  const int* f_coset = (const int*)d_in[2];
  u32* y   = (u32*)d_out;
  uint2* tw = (uint2*)d_ws;
  const int batch = in_sizes[0] >> 21;     // 8
  const int nwg = batch << 7;              // 1024 workgroups per pass

  k_gen  <<<64,  256, 0, stream>>>(tw, f_intt);
  k_passA<<<nwg, 512, 0, stream>>>(x, y, tw, f_intt, f_coset);
  k_passB<<<nwg, 512, 0, stream>>>(y, tw);
  k_passC<<<nwg, 512, 0, stream>>>(y, tw, f_intt, f_coset);
}

// Round 3
// 181.855 us; speedup vs baseline: 2.1299x; 1.6045x over previous
//
#include <hip/hip_runtime.h>
#include <stdint.h>

typedef unsigned int u32;
typedef unsigned long long u64;

#define MOD_P 2013265921u

// uint2 table offsets (index in uint2 units): (value, shoup) pairs
#define T_A      0        // w^{(i>>7)*(i&127)}        [ka][jc] product table, 16384
#define T_B      16384    // (w^128)^{(i>>7)*(i&127)}  [kb][jc] product table, 16384
#define T_W128P  32768    // (w^128)^i, i<16384
#define T_RP     49152    // (w^16384)^i, i<64  (order-128 stage roots)
#define T_CLP    49216    // c^i, i<16384       (coset low)
#define T_CHP    65600    // c^(16384 i), i<128 (coset high)
#define T_NINV   65728    // (n^-1)

__device__ __forceinline__ u32 mul64mod(u32 a, u32 b){ return (u32)((u64)a * b % MOD_P); }

__device__ u32 powmod(u32 b, u32 e){
  u32 r = 1;
  while (e){ if (e & 1) r = mul64mod(r, b); b = mul64mod(b, b); e >>= 1; }
  return r;
}

__device__ __forceinline__ u32 shoup_of(u32 v){ return (u32)(((u64)v << 32) / MOD_P); }

// Shoup modular multiply with precomputed (w, floor(w*2^32/P)). Result in [0,P).
__device__ __forceinline__ u32 mul_shoup(u32 a, uint2 t){
  u32 q = __umulhi(a, t.y);
  u32 r = a * t.x - q * MOD_P;          // exact mod 2^32, true value < 2P
  return (r >= MOD_P) ? r - MOD_P : r;
}

__device__ __forceinline__ int br7(int x){ return (int)(__brev((u32)x) >> 25); }

// XOR-swizzled LDS index for a 128x128 u32 tile.
__device__ __forceinline__ int lidx(int r, int c){ return (r << 7) | (c ^ (r & 31)); }

// ---------------- table generation (per launch; reads direction flag) -------
extern "C" __global__ void k_gen(uint2* __restrict__ tw, const int* __restrict__ f_intt){
  const int idx = blockIdx.x * 256 + threadIdx.x;   // 0..16383
  const int intt = f_intt[0];
  u32 w = powmod(31u, (MOD_P - 1) >> 21);     // primitive 2^21-th root
  if (intt) w = powmod(w, MOD_P - 2);
  const u32 w128 = powmod(w, 128u);
  const int hi = idx >> 7, lo = idx & 127;

  u32 a = powmod(w, (u32)(hi * lo));
  tw[T_A + idx] = make_uint2(a, shoup_of(a));
  u32 b = powmod(w128, (u32)(hi * lo));
  tw[T_B + idx] = make_uint2(b, shoup_of(b));
  u32 v2 = powmod(w128, (u32)idx);
  tw[T_W128P + idx] = make_uint2(v2, shoup_of(v2));
  u32 c = intt ? powmod(7u, MOD_P - 2) : 7u;
  u32 cv = powmod(c, (u32)idx);
  tw[T_CLP + idx] = make_uint2(cv, shoup_of(cv));
  if (idx < 128){
    u32 h = powmod(c, (u32)idx << 14);
    tw[T_CHP + idx] = make_uint2(h, shoup_of(h));
  }
  if (idx < 64){
    u32 rv = powmod(powmod(w, 1u << 14), (u32)idx);
    tw[T_RP + idx] = make_uint2(rv, shoup_of(rv));
  }
  if (idx == 0){
    u32 ninv = powmod(1u << 21, MOD_P - 2);
    tw[T_NINV] = make_uint2(ninv, shoup_of(ninv));
  }
}

// -------- 128-pt DIF NTT along the ROW dimension (1024 threads) -------------
// natural-order in, out[r] holds frequency br7(r)
__device__ void ntt128_rows(u32* lds, const uint2* __restrict__ tw){
  const int t = threadIdx.x;
  const int col = t & 127;
  const int bhi = t >> 7;                 // 0..7, wave-uniform
  for (int s = 6; s >= 0; --s){
    const int h = 1 << s;
    __syncthreads();
    #pragma unroll
    for (int i = 0; i < 8; ++i){
      int beta = bhi + (i << 3);          // butterfly index 0..63
      int tt = beta & (h - 1);
      int p1 = ((beta ^ tt) << 1) | tt;
      int p2 = p1 + h;
      u32 e = lds[lidx(p1, col)];
      u32 o = lds[lidx(p2, col)];
      u32 sum = e + o;           if (sum >= MOD_P) sum -= MOD_P;
      u32 dif = e + MOD_P - o;   if (dif >= MOD_P) dif -= MOD_P;
      dif = mul_shoup(dif, tw[T_RP + (tt << (6 - s))]);
      lds[lidx(p1, col)] = sum;
      lds[lidx(p2, col)] = dif;
    }
  }
  __syncthreads();
}

// -------- 128-pt DIF NTT along the COLUMN dimension (1024 threads) ----------
__device__ void ntt128_cols(u32* lds, const uint2* __restrict__ tw){
  const int t = threadIdx.x;
  const int beta = t & 63;
  const int rhi = t >> 6;                 // 0..15
  for (int s = 6; s >= 0; --s){
    const int h = 1 << s;
    const int tt = beta & (h - 1);
    const int p1 = ((beta ^ tt) << 1) | tt;
    const int p2 = p1 + h;
    const uint2 tv = tw[T_RP + (tt << (6 - s))];
    __syncthreads();
    #pragma unroll
    for (int i = 0; i < 8; ++i){
      int row = rhi + (i << 4);
      u32 e = lds[lidx(row, p1)];
      u32 o = lds[lidx(row, p2)];
      u32 sum = e + o;           if (sum >= MOD_P) sum -= MOD_P;
      u32 dif = e + MOD_P - o;   if (dif >= MOD_P) dif -= MOD_P;
      dif = mul_shoup(dif, tv);
      lds[lidx(row, p1)] = sum;
      lds[lidx(row, p2)] = dif;
    }
  }
  __syncthreads();
}

// ---------------- pass A: NTT over ja (stride 16384), d_in -> d_out ---------
extern "C" __global__ void __launch_bounds__(1024, 8) k_passA(
    const u32* __restrict__ x, u32* __restrict__ y, const uint2* __restrict__ tw,
    const int* __restrict__ f_intt, const int* __restrict__ f_coset)
{
  __shared__ u32 lds[16384];
  const int wg = blockIdx.x;
  const int batch = wg >> 7;
  const int jb = wg & 127;
  const u32* xb = x + ((size_t)batch << 21);
  u32* yb = y + ((size_t)batch << 21);
  const int t = threadIdx.x;
  const int q = t & 31;                  // quad-column 0..31
  const int roff = t >> 5;               // 0..31
  const bool pre = (f_intt[0] == 0) && (f_coset[0] != 0);
  #pragma unroll
  for (int i = 0; i < 4; ++i){
    int ja = roff + (i << 5);
    uint4 v4 = *(const uint4*)(xb + ((size_t)ja << 14) + (jb << 7) + (q << 2));
    u32 vv[4] = {v4.x, v4.y, v4.z, v4.w};
    #pragma unroll
    for (int j = 0; j < 4; ++j){
      u32 v = vv[j];
      if (v >= MOD_P) v -= MOD_P;
      if (pre){
        int jlo = (jb << 7) + (q << 2) + j;
        v = mul_shoup(v, tw[T_CLP + jlo]);
        v = mul_shoup(v, tw[T_CHP + ja]);
      }
      lds[lidx(ja, (q << 2) + j)] = v;
    }
  }
  ntt128_rows(lds, tw);
  #pragma unroll
  for (int i = 0; i < 4; ++i){
    int r = roff + (i << 5);
    int ka = br7(r);
    uint2 t2 = tw[T_W128P + ka * jb];    // near-uniform per wave
    u32 ov[4];
    #pragma unroll
    for (int j = 0; j < 4; ++j){
      int c = (q << 2) + j;
      u32 v = lds[lidx(r, c)];
      v = mul_shoup(v, tw[T_A + (ka << 7) + c]);   // coalesced product table
      v = mul_shoup(v, t2);
      ov[j] = v;
    }
    *(uint4*)(yb + ((size_t)ka << 14) + (jb << 7) + (q << 2)) = make_uint4(ov[0], ov[1], ov[2], ov[3]);
  }
}

// ---------------- pass B: NTT over jb (contiguous slab, in-place) -----------
extern "C" __global__ void __launch_bounds__(1024, 8) k_passB(
    u32* __restrict__ y, const uint2* __restrict__ tw)
{
  __shared__ u32 lds[16384];
  const int wg = blockIdx.x;
  const int batch = wg >> 7;
  const int ka = wg & 127;
  u32* yb = y + ((size_t)batch << 21) + ((size_t)ka << 14);
  const int t = threadIdx.x;
  const int q = t & 31;
  const int roff = t >> 5;
  #pragma unroll
  for (int i = 0; i < 4; ++i){
    int jb = roff + (i << 5);
    uint4 v4 = *(const uint4*)(yb + (jb << 7) + (q << 2));
    lds[lidx(jb, (q << 2) + 0)] = v4.x;
    lds[lidx(jb, (q << 2) + 1)] = v4.y;
    lds[lidx(jb, (q << 2) + 2)] = v4.z;
    lds[lidx(jb, (q << 2) + 3)] = v4.w;
  }
  ntt128_rows(lds, tw);
  #pragma unroll
  for (int i = 0; i < 4; ++i){
    int r = roff + (i << 5);
    int kb = br7(r);
    u32 ov[4];
    #pragma unroll
    for (int j = 0; j < 4; ++j){
      int c = (q << 2) + j;
      u32 v = lds[lidx(r, c)];
      v = mul_shoup(v, tw[T_B + (kb << 7) + c]);   // coalesced product table
      ov[j] = v;
    }
    *(uint4*)(yb + (kb << 7) + (q << 2)) = make_uint4(ov[0], ov[1], ov[2], ov[3]);
  }
}

// ------- pass C: NTT over jc + in-place plane transpose to final order ------
extern "C" __global__ void __launch_bounds__(1024, 8) k_passC(
    u32* __restrict__ y, const uint2* __restrict__ tw,
    const int* __restrict__ f_intt, const int* __restrict__ f_coset)
{
  __shared__ u32 lds[16384];
  const int wg = blockIdx.x;
  const int batch = wg >> 7;
  const int kb = wg & 127;
  u32* yb = y + ((size_t)batch << 21);
  const int t = threadIdx.x;
  const int q = t & 31;
  const int roff = t >> 5;
  #pragma unroll
  for (int i = 0; i < 4; ++i){
    int ka = roff + (i << 5);
    uint4 v4 = *(const uint4*)(yb + ((size_t)ka << 14) + (kb << 7) + (q << 2));
    lds[lidx(ka, (q << 2) + 0)] = v4.x;
    lds[lidx(ka, (q << 2) + 1)] = v4.y;
    lds[lidx(ka, (q << 2) + 2)] = v4.z;
    lds[lidx(ka, (q << 2) + 3)] = v4.w;
  }
  ntt128_cols(lds, tw);
  const int intt = f_intt[0];
  const int coset = f_coset[0];
  const int ka2 = t & 127;
  const int rr = t >> 7;                 // 0..7
  #pragma unroll
  for (int i = 0; i < 16; ++i){
    int pos = rr + (i << 3);
    int kc = br7(pos);
    u32 v = lds[lidx(ka2, pos)];
    if (intt){
      v = mul_shoup(v, tw[T_NINV]);
      if (coset){
        int klo = (kb << 7) + ka2;
        v = mul_shoup(v, tw[T_CLP + klo]);
        v = mul_shoup(v, tw[T_CHP + kc]);
      }
    }
    yb[((size_t)kc << 14) + (kb << 7) + ka2] = v;   // flat = ka + 128*kb + 16384*kc
  }
}

extern "C" void kernel_launch(void* const* d_in, const int* in_sizes, int n_in,
                              void* d_out, int out_size, void* d_ws, size_t ws_size,
                              hipStream_t stream)
{
  const u32* x = (const u32*)d_in[0];
  const int* f_intt  = (const int*)d_in[1];
  const int* f_coset = (const int*)d_in[2];
  u32* y   = (u32*)d_out;
  uint2* tw = (uint2*)d_ws;
  const int batch = in_sizes[0] >> 21;     // 8
  const int nwg = batch << 7;              // 1024 workgroups per pass

  k_gen  <<<64,   256, 0, stream>>>(tw, f_intt);
  k_passA<<<nwg, 1024, 0, stream>>>(x, y, tw, f_intt, f_coset);
  k_passB<<<nwg, 1024, 0, stream>>>(y, tw);
  k_passC<<<nwg, 1024, 0, stream>>>(y, tw, f_intt, f_coset);
}

// Round 4
// 106.287 us; speedup vs baseline: 3.6443x; 1.7110x over previous
//
#include <hip/hip_runtime.h>
#include <stdint.h>

typedef unsigned int u32;
typedef unsigned long long u64;

#define MOD_P 2013265921u

// uint2 table offsets (index in uint2 units): (value, shoup) pairs
#define T_A      0        // w^{(i>>7)*(i&127)}        [ka][jc] product table, 16384
#define T_B      16384    // (w^128)^{(i>>7)*(i&127)}  [kb][jc] product table, 16384
#define T_W128P  32768    // (w^128)^i, i<16384
#define T_RP     49152    // (w^16384)^i, i<64  (order-128 stage roots)
#define T_CLP    49216    // c^i, i<16384       (coset low)
#define T_CHP    65600    // c^(16384 i), i<128 (coset high)
#define T_NINV   65728    // (n^-1)

__device__ __forceinline__ u32 mul64mod(u32 a, u32 b){ return (u32)((u64)a * b % MOD_P); }

__device__ u32 powmod(u32 b, u32 e){
  u32 r = 1;
  while (e){ if (e & 1) r = mul64mod(r, b); b = mul64mod(b, b); e >>= 1; }
  return r;
}

__device__ __forceinline__ u32 shoup_of(u32 v){ return (u32)(((u64)v << 32) / MOD_P); }

// Shoup modular multiply with precomputed (w, floor(w*2^32/P)). Result in [0,P).
__device__ __forceinline__ u32 mul_shoup(u32 a, uint2 t){
  u32 q = __umulhi(a, t.y);
  u32 r = a * t.x - q * MOD_P;          // exact mod 2^32, true value < 2P
  return (r >= MOD_P) ? r - MOD_P : r;
}

__device__ __forceinline__ constexpr int rev4(int m){
  return ((m&1)<<3) | ((m&2)<<1) | ((m&4)>>1) | ((m&8)>>3);
}

// DIF butterfly: (x,y) -> (x+y, (x-y)*t)
__device__ __forceinline__ void bf(u32 &x, u32 &y, uint2 t){
  u32 s = x + y;           if (s >= MOD_P) s -= MOD_P;
  u32 d = x + MOD_P - y;   if (d >= MOD_P) d -= MOD_P;
  x = s; y = mul_shoup(d, t);
}
__device__ __forceinline__ void bf0(u32 &x, u32 &y){   // twiddle = 1
  u32 s = x + y;           if (s >= MOD_P) s -= MOD_P;
  u32 d = x + MOD_P - y;   if (d >= MOD_P) d -= MOD_P;
  x = s; y = d;
}

// phase-1: thread rows r = b + 8m (m=0..15), DIF stages h=64,32,16,8
__device__ __forceinline__ void stages_p1(u32 v[16], int b, const uint2* __restrict__ twl){
  #pragma unroll
  for (int m = 0; m < 8; ++m) bf(v[m], v[m+8], twl[b + 8*m]);               // s=6
  #pragma unroll
  for (int g = 0; g < 2; ++g)
    #pragma unroll
    for (int m = 0; m < 4; ++m) bf(v[g*8+m], v[g*8+m+4], twl[(b + 8*m) << 1]); // s=5
  #pragma unroll
  for (int g = 0; g < 4; ++g)
    #pragma unroll
    for (int m = 0; m < 2; ++m) bf(v[g*4+m], v[g*4+m+2], twl[(b + 8*m) << 2]); // s=4
  #pragma unroll
  for (int k = 0; k < 8; ++k) bf(v[2*k], v[2*k+1], twl[b << 3]);            // s=3
}
// phase-2: thread rows r = 16b + m, DIF stages h=4,2,1
__device__ __forceinline__ void stages_p2(u32 v[16], const uint2* __restrict__ twl){
  #pragma unroll
  for (int g = 0; g < 2; ++g)
    #pragma unroll
    for (int m = 0; m < 4; ++m) bf(v[g*8+m], v[g*8+m+4], twl[m << 4]);      // s=2
  #pragma unroll
  for (int g = 0; g < 4; ++g)
    #pragma unroll
    for (int m = 0; m < 2; ++m) bf(v[g*4+m], v[g*4+m+2], twl[m << 5]);      // s=1
  #pragma unroll
  for (int k = 0; k < 8; ++k) bf0(v[2*k], v[2*k+1]);                        // s=0 (e=0)
}

// ---------------- table generation (per launch; reads direction flag) -------
extern "C" __global__ void k_gen(uint2* __restrict__ tw, const int* __restrict__ f_intt){
  const int idx = blockIdx.x * 256 + threadIdx.x;   // 0..16383
  const int intt = f_intt[0];
  u32 w = powmod(31u, (MOD_P - 1) >> 21);     // primitive 2^21-th root
  if (intt) w = powmod(w, MOD_P - 2);
  const u32 w128 = powmod(w, 128u);
  const int hi = idx >> 7, lo = idx & 127;

  u32 a = powmod(w, (u32)(hi * lo));
  tw[T_A + idx] = make_uint2(a, shoup_of(a));
  u32 b = powmod(w128, (u32)(hi * lo));
  tw[T_B + idx] = make_uint2(b, shoup_of(b));
  u32 v2 = powmod(w128, (u32)idx);
  tw[T_W128P + idx] = make_uint2(v2, shoup_of(v2));
  u32 c = intt ? powmod(7u, MOD_P - 2) : 7u;
  u32 cv = powmod(c, (u32)idx);
  tw[T_CLP + idx] = make_uint2(cv, shoup_of(cv));
  if (idx < 128){
    u32 h = powmod(c, (u32)idx << 14);
    tw[T_CHP + idx] = make_uint2(h, shoup_of(h));
  }
  if (idx < 64){
    u32 rv = powmod(powmod(w, 1u << 14), (u32)idx);
    tw[T_RP + idx] = make_uint2(rv, shoup_of(rv));
  }
  if (idx == 0){
    u32 ninv = powmod(1u << 21, MOD_P - 2);
    tw[T_NINV] = make_uint2(ninv, shoup_of(ninv));
  }
}

// ---------------- pass A: NTT over ja (stride 16384), d_in -> d_out ---------
// grid: batch*128*2, WG=(batch, jb, jc-half); thread=(b, c): 16 elems in reg
extern "C" __global__ void __launch_bounds__(512, 8) k_passA(
    const u32* __restrict__ x, u32* __restrict__ y, const uint2* __restrict__ tw,
    const int* __restrict__ f_intt, const int* __restrict__ f_coset)
{
  __shared__ u32 lds[8192];               // [128 rows][64 cols], row access only
  const int wg = blockIdx.x;
  const int half = wg & 1;
  const int jb = (wg >> 1) & 127;
  const int batch = wg >> 8;
  const int t = threadIdx.x;
  const int c = t & 63;
  const int b = __builtin_amdgcn_readfirstlane(t >> 6);   // 0..7, wave-uniform
  const int jc = (half << 6) | c;
  const u32* xb = x + ((size_t)batch << 21);
  u32* yb = y + ((size_t)batch << 21);
  const uint2* twl = tw + T_RP;

  u32 v[16];
  #pragma unroll
  for (int m = 0; m < 16; ++m){
    u32 a = xb[((size_t)(b + 8*m) << 14) + (jb << 7) + jc];
    v[m] = (a >= MOD_P) ? a - MOD_P : a;
  }
  if ((f_intt[0] == 0) && (f_coset[0] != 0)){
    uint2 cl = tw[T_CLP + (jb << 7) + jc];
    #pragma unroll
    for (int m = 0; m < 16; ++m){
      v[m] = mul_shoup(v[m], cl);
      v[m] = mul_shoup(v[m], tw[T_CHP + b + 8*m]);
    }
  }
  stages_p1(v, b, twl);
  #pragma unroll
  for (int m = 0; m < 16; ++m) lds[((b + 8*m) << 6) | c] = v[m];
  __syncthreads();
  #pragma unroll
  for (int m = 0; m < 16; ++m) v[m] = lds[((16*b + m) << 6) | c];
  stages_p2(v, twl);
  const int rb = ((b&1)<<2) | (b&2) | ((b&4)>>2);          // rev3(b)
  #pragma unroll
  for (int m = 0; m < 16; ++m){
    const int ka = (rev4(m) << 3) | rb;                    // br7(16b+m)
    u32 vv = mul_shoup(v[m], tw[T_A + (ka << 7) + jc]);
    vv = mul_shoup(vv, tw[T_W128P + ka * jb]);
    yb[((size_t)ka << 14) + (jb << 7) + jc] = vv;
  }
}

// ---------------- pass B: NTT over jb (contiguous slab, in-place) -----------
extern "C" __global__ void __launch_bounds__(512, 8) k_passB(
    u32* __restrict__ y, const uint2* __restrict__ tw)
{
  __shared__ u32 lds[8192];
  const int wg = blockIdx.x;
  const int half = wg & 1;
  const int ka = (wg >> 1) & 127;
  const int batch = wg >> 8;
  const int t = threadIdx.x;
  const int c = t & 63;
  const int b = __builtin_amdgcn_readfirstlane(t >> 6);
  const int jc = (half << 6) | c;
  u32* yb = y + ((size_t)batch << 21) + ((size_t)ka << 14);
  const uint2* twl = tw + T_RP;

  u32 v[16];
  #pragma unroll
  for (int m = 0; m < 16; ++m) v[m] = yb[((b + 8*m) << 7) + jc];
  stages_p1(v, b, twl);
  #pragma unroll
  for (int m = 0; m < 16; ++m) lds[((b + 8*m) << 6) | c] = v[m];
  __syncthreads();
  #pragma unroll
  for (int m = 0; m < 16; ++m) v[m] = lds[((16*b + m) << 6) | c];
  stages_p2(v, twl);
  const int rb = ((b&1)<<2) | (b&2) | ((b&4)>>2);
  #pragma unroll
  for (int m = 0; m < 16; ++m){
    const int kb = (rev4(m) << 3) | rb;
    u32 vv = mul_shoup(v[m], tw[T_B + (kb << 7) + jc]);
    yb[(kb << 7) + jc] = vv;
  }
}

// ------- pass C: NTT over jc + in-place plane transpose to final order ------
// grid: batch*128*2, WG=(batch, kb, ka-half); LDS tile [jc=128][ka=64] pad 65
extern "C" __global__ void __launch_bounds__(512, 8) k_passC(
    u32* __restrict__ y, const uint2* __restrict__ tw,
    const int* __restrict__ f_intt, const int* __restrict__ f_coset)
{
  __shared__ u32 lds[65 * 128];
  const int wg = blockIdx.x;
  const int half = wg & 1;
  const int kb = (wg >> 1) & 127;
  const int batch = wg >> 8;
  u32* yb = y + ((size_t)batch << 21);
  const u32* base = yb + (kb << 7);
  const int t = threadIdx.x;
  {   // stage-in: transpose [ka][jc] -> LDS[jc][ka]
    const int q = t & 31;                // jc quad
    const int rr = t >> 5;               // 0..15
    #pragma unroll
    for (int i = 0; i < 4; ++i){
      int kaL = rr + 16*i;
      uint4 v4 = *(const uint4*)(base + ((size_t)((half << 6) + kaL) << 14) + (q << 2));
      lds[65*(4*q+0) + kaL] = v4.x;
      lds[65*(4*q+1) + kaL] = v4.y;
      lds[65*(4*q+2) + kaL] = v4.z;
      lds[65*(4*q+3) + kaL] = v4.w;
    }
  }
  __syncthreads();
  const int a = t & 63;
  const int b = __builtin_amdgcn_readfirstlane(t >> 6);
  const uint2* twl = tw + T_RP;
  u32 v[16];
  #pragma unroll
  for (int m = 0; m < 16; ++m) v[m] = lds[65*(b + 8*m) + a];
  stages_p1(v, b, twl);
  #pragma unroll
  for (int m = 0; m < 16; ++m) lds[65*(b + 8*m) + a] = v[m];
  __syncthreads();
  #pragma unroll
  for (int m = 0; m < 16; ++m) v[m] = lds[65*(16*b + m) + a];
  stages_p2(v, twl);
  const int rb = ((b&1)<<2) | (b&2) | ((b&4)>>2);
  const int kaG = (half << 6) | a;
  const int intt = f_intt[0];
  const int coset = f_coset[0];
  #pragma unroll
  for (int m = 0; m < 16; ++m){
    const int kc = (rev4(m) << 3) | rb;
    u32 vv = v[m];
    if (intt){
      vv = mul_shoup(vv, tw[T_NINV]);
      if (coset){
        vv = mul_shoup(vv, tw[T_CLP + (kb << 7) + kaG]);
        vv = mul_shoup(vv, tw[T_CHP + kc]);
      }
    }
    yb[((size_t)kc << 14) + (kb << 7) + kaG] = vv;   // flat = ka + 128*kb + 16384*kc
  }
}

extern "C" void kernel_launch(void* const* d_in, const int* in_sizes, int n_in,
                              void* d_out, int out_size, void* d_ws, size_t ws_size,
                              hipStream_t stream)
{
  const u32* x = (const u32*)d_in[0];
  const int* f_intt  = (const int*)d_in[1];
  const int* f_coset = (const int*)d_in[2];
  u32* y   = (u32*)d_out;
  uint2* tw = (uint2*)d_ws;
  const int batch = in_sizes[0] >> 21;     // 8
  const int nwg = batch << 8;              // 2048 workgroups per pass

  k_gen  <<<64,  256, 0, stream>>>(tw, f_intt);
  k_passA<<<nwg, 512, 0, stream>>>(x, y, tw, f_intt, f_coset);
  k_passB<<<nwg, 512, 0, stream>>>(y, tw);
  k_passC<<<nwg, 512, 0, stream>>>(y, tw, f_intt, f_coset);
}

// Round 5
// 103.818 us; speedup vs baseline: 3.7309x; 1.0238x over previous
//
#include <hip/hip_runtime.h>
#include <stdint.h>

typedef unsigned int u32;
typedef unsigned long long u64;

#define MOD_P 2013265921u

// uint2 table offsets (index in uint2 units): (value, shoup) pairs
#define T_A      0        // w^{(i>>7)*(i&127)}        [ka][jc] product table, 16384
#define T_B      16384    // (w^128)^{(i>>7)*(i&127)}  [kb][jc] product table, 16384
#define T_W128P  32768    // (w^128)^i, i<16384
#define T_RP     49152    // (w^16384)^i, i<64  (order-128 stage roots)
#define T_CLP    49216    // c^i, i<16384       (coset low)
#define T_CHP    65600    // c^(16384 i), i<128 (coset high)
#define T_NINV   65728    // (n^-1)

__device__ __forceinline__ u32 mul64mod(u32 a, u32 b){ return (u32)((u64)a * b % MOD_P); }

__device__ u32 powmod(u32 b, u32 e){
  u32 r = 1;
  while (e){ if (e & 1) r = mul64mod(r, b); b = mul64mod(b, b); e >>= 1; }
  return r;
}

__device__ __forceinline__ u32 shoup_of(u32 v){ return (u32)(((u64)v << 32) / MOD_P); }

// reduce a in [0,2P) to [0,P): unsigned-wrap min trick (v_sub + v_min_u32)
__device__ __forceinline__ u32 redP(u32 a){
  u32 b = a - MOD_P;
  return b < a ? b : a;
}

// Shoup modular multiply with precomputed (w, floor(w*2^32/P)). Result in [0,P).
__device__ __forceinline__ u32 mul_shoup(u32 a, uint2 t){
  u32 q = __umulhi(a, t.y);
  u32 r = a * t.x - q * MOD_P;          // exact mod 2^32, true value < 2P
  return redP(r);
}

__device__ __forceinline__ constexpr int rev4(int m){
  return ((m&1)<<3) | ((m&2)<<1) | ((m&4)>>1) | ((m&8)>>3);
}

// DIF butterfly: (x,y) -> (x+y, (x-y)*t)
__device__ __forceinline__ void bf(u32 &x, u32 &y, uint2 t){
  u32 s = redP(x + y);
  u32 d = redP(x - y + MOD_P);
  x = s; y = mul_shoup(d, t);
}
__device__ __forceinline__ void bf0(u32 &x, u32 &y){   // twiddle = 1
  u32 s = redP(x + y);
  u32 d = redP(x - y + MOD_P);
  x = s; y = d;
}

// phase-1: thread rows r = b + 8m (m=0..15), DIF stages h=64,32,16,8
__device__ __forceinline__ void stages_p1(u32 v[16], int b, const uint2* __restrict__ twl){
  #pragma unroll
  for (int m = 0; m < 8; ++m) bf(v[m], v[m+8], twl[b + 8*m]);               // s=6
  #pragma unroll
  for (int g = 0; g < 2; ++g)
    #pragma unroll
    for (int m = 0; m < 4; ++m) bf(v[g*8+m], v[g*8+m+4], twl[(b + 8*m) << 1]); // s=5
  #pragma unroll
  for (int g = 0; g < 4; ++g)
    #pragma unroll
    for (int m = 0; m < 2; ++m) bf(v[g*4+m], v[g*4+m+2], twl[(b + 8*m) << 2]); // s=4
  #pragma unroll
  for (int k = 0; k < 8; ++k) bf(v[2*k], v[2*k+1], twl[b << 3]);            // s=3
}
// phase-2: thread rows r = 16b + m, DIF stages h=4,2,1
__device__ __forceinline__ void stages_p2(u32 v[16], const uint2* __restrict__ twl){
  #pragma unroll
  for (int g = 0; g < 2; ++g)
    #pragma unroll
    for (int m = 0; m < 4; ++m) bf(v[g*8+m], v[g*8+m+4], twl[m << 4]);      // s=2
  #pragma unroll
  for (int g = 0; g < 4; ++g)
    #pragma unroll
    for (int m = 0; m < 2; ++m) bf(v[g*4+m], v[g*4+m+2], twl[m << 5]);      // s=1
  #pragma unroll
  for (int k = 0; k < 8; ++k) bf0(v[2*k], v[2*k+1]);                        // s=0 (e=0)
}

// ---------------- table generation (per launch; reads direction flag) -------
extern "C" __global__ void k_gen(uint2* __restrict__ tw, const int* __restrict__ f_intt){
  const int idx = blockIdx.x * 256 + threadIdx.x;   // 0..16383
  const int intt = f_intt[0];
  u32 w = powmod(31u, (MOD_P - 1) >> 21);     // primitive 2^21-th root
  if (intt) w = powmod(w, MOD_P - 2);
  const u32 w128 = powmod(w, 128u);
  const int hi = idx >> 7, lo = idx & 127;

  u32 a = powmod(w, (u32)(hi * lo));
  tw[T_A + idx] = make_uint2(a, shoup_of(a));
  u32 b = powmod(w128, (u32)(hi * lo));
  tw[T_B + idx] = make_uint2(b, shoup_of(b));
  u32 v2 = powmod(w128, (u32)idx);
  tw[T_W128P + idx] = make_uint2(v2, shoup_of(v2));
  u32 c = intt ? powmod(7u, MOD_P - 2) : 7u;
  u32 cv = powmod(c, (u32)idx);
  tw[T_CLP + idx] = make_uint2(cv, shoup_of(cv));
  if (idx < 128){
    u32 h = powmod(c, (u32)idx << 14);
    tw[T_CHP + idx] = make_uint2(h, shoup_of(h));
  }
  if (idx < 64){
    u32 rv = powmod(powmod(w, 1u << 14), (u32)idx);
    tw[T_RP + idx] = make_uint2(rv, shoup_of(rv));
  }
  if (idx == 0){
    u32 ninv = powmod(1u << 21, MOD_P - 2);
    tw[T_NINV] = make_uint2(ninv, shoup_of(ninv));
  }
}

// ---------------- pass A: NTT over ja (stride 16384), d_in -> d_out ---------
// grid: batch*128*2, WG=(batch, jb, jc-half); thread=(b, c): 16 elems in reg
extern "C" __global__ void __launch_bounds__(512, 8) k_passA(
    const u32* __restrict__ x, u32* __restrict__ y, const uint2* __restrict__ tw,
    const int* __restrict__ f_intt, const int* __restrict__ f_coset)
{
  __shared__ u32 lds[8192];               // [128 rows][64 cols], row access only
  const int wg = blockIdx.x;
  const int half = wg & 1;
  const int jb = (wg >> 1) & 127;
  const int batch = wg >> 8;
  const int t = threadIdx.x;
  const int c = t & 63;
  const int b = __builtin_amdgcn_readfirstlane(t >> 6);   // 0..7, wave-uniform
  const int jc = (half << 6) | c;
  const u32* xb = x + ((size_t)batch << 21);
  u32* yb = y + ((size_t)batch << 21);
  const uint2* twl = tw + T_RP;

  u32 v[16];
  #pragma unroll
  for (int m = 0; m < 16; ++m){
    u32 a = xb[((size_t)(b + 8*m) << 14) + (jb << 7) + jc];
    v[m] = redP(a);
  }
  if ((f_intt[0] == 0) && (f_coset[0] != 0)){
    uint2 cl = tw[T_CLP + (jb << 7) + jc];
    #pragma unroll
    for (int m = 0; m < 16; ++m){
      v[m] = mul_shoup(v[m], cl);
      v[m] = mul_shoup(v[m], tw[T_CHP + b + 8*m]);
    }
  }
  stages_p1(v, b, twl);
  #pragma unroll
  for (int m = 0; m < 16; ++m) lds[((b + 8*m) << 6) | c] = v[m];
  __syncthreads();
  #pragma unroll
  for (int m = 0; m < 16; ++m) v[m] = lds[((16*b + m) << 6) | c];
  stages_p2(v, twl);
  const int rb = ((b&1)<<2) | (b&2) | ((b&4)>>2);          // rev3(b)
  #pragma unroll
  for (int m = 0; m < 16; ++m){
    const int ka = (rev4(m) << 3) | rb;                    // br7(16b+m)
    u32 vv = mul_shoup(v[m], tw[T_A + (ka << 7) + jc]);
    vv = mul_shoup(vv, tw[T_W128P + ka * jb]);
    yb[((size_t)ka << 14) + (jb << 7) + jc] = vv;
  }
}

// ---------------- pass B: NTT over jb (contiguous slab, in-place) -----------
extern "C" __global__ void __launch_bounds__(512, 8) k_passB(
    u32* __restrict__ y, const uint2* __restrict__ tw)
{
  __shared__ u32 lds[8192];
  const int wg = blockIdx.x;
  const int half = wg & 1;
  const int ka = (wg >> 1) & 127;
  const int batch = wg >> 8;
  const int t = threadIdx.x;
  const int c = t & 63;
  const int b = __builtin_amdgcn_readfirstlane(t >> 6);
  const int jc = (half << 6) | c;
  u32* yb = y + ((size_t)batch << 21) + ((size_t)ka << 14);
  const uint2* twl = tw + T_RP;

  u32 v[16];
  #pragma unroll
  for (int m = 0; m < 16; ++m) v[m] = yb[((b + 8*m) << 7) + jc];
  stages_p1(v, b, twl);
  #pragma unroll
  for (int m = 0; m < 16; ++m) lds[((b + 8*m) << 6) | c] = v[m];
  __syncthreads();
  #pragma unroll
  for (int m = 0; m < 16; ++m) v[m] = lds[((16*b + m) << 6) | c];
  stages_p2(v, twl);
  const int rb = ((b&1)<<2) | (b&2) | ((b&4)>>2);
  #pragma unroll
  for (int m = 0; m < 16; ++m){
    const int kb = (rev4(m) << 3) | rb;
    u32 vv = mul_shoup(v[m], tw[T_B + (kb << 7) + jc]);
    yb[(kb << 7) + jc] = vv;
  }
}

// ------- pass C: NTT over jc + in-place plane transpose to final order ------
// grid: batch*128*2, WG=(batch, kb, ka-half)
// LDS tile [row=jc(128)][col=ka(64)] with XOR swizzle col^(row>>2): 2-way max
__device__ __forceinline__ int cidx(int row, int a){
  return (row << 6) | (a ^ (row >> 2));
}
extern "C" __global__ void __launch_bounds__(512, 8) k_passC(
    u32* __restrict__ y, const uint2* __restrict__ tw,
    const int* __restrict__ f_intt, const int* __restrict__ f_coset)
{
  __shared__ u32 lds[8192];
  const int wg = blockIdx.x;
  const int half = wg & 1;
  const int kb = (wg >> 1) & 127;
  const int batch = wg >> 8;
  u32* yb = y + ((size_t)batch << 21);
  const u32* base = yb + (kb << 7);
  const int t = threadIdx.x;
  {   // stage-in: transpose [ka][jc] -> LDS[jc][ka]
    const int q = t & 31;                // jc quad
    const int rr = t >> 5;               // 0..15
    #pragma unroll
    for (int i = 0; i < 4; ++i){
      int kaL = rr + 16*i;
      uint4 v4 = *(const uint4*)(base + ((size_t)((half << 6) + kaL) << 14) + (q << 2));
      lds[cidx(4*q+0, kaL)] = v4.x;
      lds[cidx(4*q+1, kaL)] = v4.y;
      lds[cidx(4*q+2, kaL)] = v4.z;
      lds[cidx(4*q+3, kaL)] = v4.w;
    }
  }
  __syncthreads();
  const int a = t & 63;
  const int b = __builtin_amdgcn_readfirstlane(t >> 6);
  const uint2* twl = tw + T_RP;
  u32 v[16];
  #pragma unroll
  for (int m = 0; m < 16; ++m) v[m] = lds[cidx(b + 8*m, a)];
  stages_p1(v, b, twl);
  #pragma unroll
  for (int m = 0; m < 16; ++m) lds[cidx(b + 8*m, a)] = v[m];
  __syncthreads();
  #pragma unroll
  for (int m = 0; m < 16; ++m) v[m] = lds[cidx(16*b + m, a)];
  stages_p2(v, twl);
  const int rb = ((b&1)<<2) | (b&2) | ((b&4)>>2);
  const int kaG = (half << 6) | a;
  const int intt = f_intt[0];
  const int coset = f_coset[0];
  #pragma unroll
  for (int m = 0; m < 16; ++m){
    const int kc = (rev4(m) << 3) | rb;
    u32 vv = v[m];
    if (intt){
      vv = mul_shoup(vv, tw[T_NINV]);
      if (coset){
        vv = mul_shoup(vv, tw[T_CLP + (kb << 7) + kaG]);
        vv = mul_shoup(vv, tw[T_CHP + kc]);
      }
    }
    yb[((size_t)kc << 14) + (kb << 7) + kaG] = vv;   // flat = ka + 128*kb + 16384*kc
  }
}

extern "C" void kernel_launch(void* const* d_in, const int* in_sizes, int n_in,
                              void* d_out, int out_size, void* d_ws, size_t ws_size,
                              hipStream_t stream)
{
  const u32* x = (const u32*)d_in[0];
  const int* f_intt  = (const int*)d_in[1];
  const int* f_coset = (const int*)d_in[2];
  u32* y   = (u32*)d_out;
  uint2* tw = (uint2*)d_ws;
  const int batch = in_sizes[0] >> 21;     // 8
  const int nwg = batch << 8;              // 2048 workgroups per pass

  k_gen  <<<64,  256, 0, stream>>>(tw, f_intt);
  k_passA<<<nwg, 512, 0, stream>>>(x, y, tw, f_intt, f_coset);
  k_passB<<<nwg, 512, 0, stream>>>(y, tw);
  k_passC<<<nwg, 512, 0, stream>>>(y, tw, f_intt, f_coset);
}